// Round 5
// baseline (413.884 us; speedup 1.0000x reference)
//
#include <hip/hip_runtime.h>

#define DD   121
#define NHID 15
#define NBLK 5
#define KS   11
#define IW   4096
#define OW   2043

// ---------------------------------------------------------------------------
// Flow inverse (MAF) + post-process. Single block, single wave (64 lanes).
// Incremental MADE inverse: maintain pre_h[j] = b1[j] + sum_set x[i]*W1m[j][i].
// Lane j (0..14) owns hidden unit j; lane 15 is a zero-contributing dummy.
// ---------------------------------------------------------------------------
__global__ __launch_bounds__(64) void flow_kernel(
    const float* __restrict__ kc,
    const float* __restrict__ W1, const float* __restrict__ b1,
    const float* __restrict__ W2, const float* __restrict__ b2,
    const float* __restrict__ lg, const float* __restrict__ beta,
    const float* __restrict__ mean, const float* __restrict__ var,
    float* __restrict__ kout)
{
    __shared__ float xs[DD];
    __shared__ float us[DD];
    __shared__ float W1s[NHID * DD];
    __shared__ float W2s[2 * DD * NHID + 16];   // +pad: dummy lane 15 reads 1 past row
    __shared__ float b2s[2 * DD];

    const int lane = threadIdx.x;

    for (int i = lane; i < DD; i += 64) xs[i] = kc[i];
    __syncthreads();

    for (int b = NBLK - 1; b >= 0; --b) {
        // BatchNorm inverse (eval mode): x = (x-beta)*exp(-lg)*sqrt(var+eps)+mean
        for (int i = lane; i < DD; i += 64) {
            float s = sqrtf(var[b*DD + i] + 1e-5f);
            us[i] = (xs[i] - beta[b*DD + i]) * __expf(-lg[b*DD + i]) * s + mean[b*DD + i];
        }
        // stage this block's weights into LDS
        for (int i = lane; i < NHID*DD;   i += 64) W1s[i] = W1[b*NHID*DD   + i];
        for (int i = lane; i < 2*DD*NHID; i += 64) W2s[i] = W2[b*2*DD*NHID + i];
        for (int i = lane; i < 2*DD;      i += 64) b2s[i] = b2[b*2*DD      + i];
        __syncthreads();

        const int evenb = ((b & 1) == 0);
        float pre_h = (lane < NHID) ? b1[b*NHID + lane] : 0.f;

        if (lane < 16) {
            const int j = lane;
            for (int t = 0; t < DD; ++t) {
                const int idx = evenb ? t : (DD - 1 - t);
                // output mask m2: deg_in[idx] > dh[j]  <=>  t > j
                float h  = (j < t && j < NHID) ? fmaxf(pre_h, 0.f) : 0.f;
                float pm = h * W2s[idx*NHID + j];
                float pa = h * W2s[(DD + idx)*NHID + j];
                #pragma unroll
                for (int off = 8; off >= 1; off >>= 1) {
                    pm += __shfl_xor(pm, off, 16);
                    pa += __shfl_xor(pa, off, 16);
                }
                const float m  = pm + b2s[idx];
                const float la = pa + b2s[DD + idx];
                const float xv = fmaf(us[idx], __expf(la), m);
                // hidden mask m1: dh[j] >= deg_in[idx]  <=>  j >= t
                if (j >= t && j < NHID) pre_h = fmaf(xv, W1s[j*DD + idx], pre_h);
                if (j == 0) xs[idx] = xv;
            }
        }
        __syncthreads();
    }

    // post-process: y = (sigmoid(x)-a)/(1-2a); k = y/sum(y)
    const float A = 1e-6f;
    float y0, y1 = 0.f;
    {
        float v = xs[lane];
        y0 = (1.f / (1.f + __expf(-v)) - A) / (1.f - 2.f*A);
    }
    if (lane + 64 < DD) {
        float v = xs[lane + 64];
        y1 = (1.f / (1.f + __expf(-v)) - A) / (1.f - 2.f*A);
    }
    float s = y0 + y1;
    #pragma unroll
    for (int off = 32; off >= 1; off >>= 1) s += __shfl_xor(s, off, 64);
    kout[lane] = y0 / s;
    if (lane + 64 < DD) kout[lane + 64] = y1 / s;
}

// ---------------------------------------------------------------------------
// 11x11 stride-2 valid conv, same kernel for all 3 channels.
// Block: 256 threads -> 64x32 output tile. Input tile 137x73 staged in LDS,
// parity-split by column (stride-2 -> unit stride, b128-aligned reads).
// Thread (tx=tid&15, ty=tid>>4) computes ox = ox0+4*tx+j (j=0..3),
// oy = oy0+2*ty+q (q=0..1).
// ---------------------------------------------------------------------------
#define TIX 137
#define TIY 73
#define SE  72   // padded word stride of parity arrays (multiple of 4)

__global__ __launch_bounds__(256) void conv_kernel(
    const float* __restrict__ in, const float* __restrict__ kf,
    float* __restrict__ out)
{
    __shared__ __align__(16) float E[TIY * SE];
    __shared__ __align__(16) float O[TIY * SE];
    __shared__ float kfs[DD];

    const int tid = threadIdx.x;
    const int cch = blockIdx.z;
    const int ox0 = blockIdx.x * 64;
    const int oy0 = blockIdx.y * 32;
    const int gx0 = ox0 * 2;          // multiple of 128 -> 16B aligned rows
    const int gy0 = oy0 * 2;

    if (tid < DD) kfs[tid] = kf[tid];

    const float* __restrict__ inc = in + (size_t)cch * IW * IW;
    {
        const int l = tid & 31;
        const int c4 = l * 4;                      // cols 0..124 via float4
        for (int r = tid >> 5; r < TIY; r += 8) {
            const int gy = gy0 + r;
            const float* rowp = inc + (size_t)gy * IW + gx0;
            float4 g = make_float4(0.f, 0.f, 0.f, 0.f);
            if (gy < IW) g = *(const float4*)(rowp + c4);   // cols 0..127 always in-bounds in x
            *(float2*)&E[r*SE + (c4 >> 1)] = make_float2(g.x, g.z);
            *(float2*)&O[r*SE + (c4 >> 1)] = make_float2(g.y, g.w);
            if (l < 9) {                           // tail cols 128..136 (guarded)
                const int ct = 128 + l;
                float v = 0.f;
                if (gy < IW && (gx0 + ct) < IW) v = rowp[ct];
                if (ct & 1) O[r*SE + (ct >> 1)] = v;
                else        E[r*SE + (ct >> 1)] = v;
            }
        }
    }
    __syncthreads();

    const int tx = tid & 15;
    const int ty = tid >> 4;

    float acc[2][4] = {{0.f,0.f,0.f,0.f},{0.f,0.f,0.f,0.f}};

    #pragma unroll
    for (int rw = 0; rw < 13; ++rw) {
        const int row = 4*ty + rw;
        const float4 ea = *(const float4*)&E[row*SE + 4*tx];
        const float4 eb = *(const float4*)&E[row*SE + 4*tx + 4];
        const float  ec =                  E[row*SE + 4*tx + 8];
        const float4 oa = *(const float4*)&O[row*SE + 4*tx];
        const float4 ob = *(const float4*)&O[row*SE + 4*tx + 4];
        const float ev[9] = {ea.x,ea.y,ea.z,ea.w,eb.x,eb.y,eb.z,eb.w,ec};
        const float ov[8] = {oa.x,oa.y,oa.z,oa.w,ob.x,ob.y,ob.z,ob.w};
        #pragma unroll
        for (int q = 0; q < 2; ++q) {
            const int ky = rw - 2*q;
            if (ky < 0 || ky > 10) continue;
            #pragma unroll
            for (int m = 0; m < 6; ++m) {
                const float we = kfs[ky*KS + 2*m];
                #pragma unroll
                for (int j = 0; j < 4; ++j)
                    acc[q][j] = fmaf(ev[m + j], we, acc[q][j]);
            }
            #pragma unroll
            for (int m = 0; m < 5; ++m) {
                const float wo = kfs[ky*KS + 2*m + 1];
                #pragma unroll
                for (int j = 0; j < 4; ++j)
                    acc[q][j] = fmaf(ov[m + j], wo, acc[q][j]);
            }
        }
    }

    #pragma unroll
    for (int q = 0; q < 2; ++q) {
        const int oy = oy0 + 2*ty + q;
        if (oy >= OW) continue;
        const size_t base = ((size_t)cch * OW + oy) * OW;
        #pragma unroll
        for (int j = 0; j < 4; ++j) {
            const int ox = ox0 + 4*tx + j;
            if (ox < OW) out[base + ox] = acc[q][j];
        }
    }
}

extern "C" void kernel_launch(void* const* d_in, const int* in_sizes, int n_in,
                              void* d_out, int out_size, void* d_ws, size_t ws_size,
                              hipStream_t stream)
{
    const float* in   = (const float*)d_in[0];
    const float* kc   = (const float*)d_in[1];
    const float* W1   = (const float*)d_in[2];
    const float* b1   = (const float*)d_in[3];
    const float* W2   = (const float*)d_in[4];
    const float* b2   = (const float*)d_in[5];
    const float* lg   = (const float*)d_in[6];
    const float* beta = (const float*)d_in[7];
    const float* mean = (const float*)d_in[8];
    const float* var  = (const float*)d_in[9];

    float* out  = (float*)d_out;
    float* kout = out + (size_t)3 * OW * OW;   // out_k lives at the tail of d_out

    flow_kernel<<<dim3(1), dim3(64), 0, stream>>>(kc, W1, b1, W2, b2, lg, beta, mean, var, kout);

    dim3 grid((OW + 63) / 64, (OW + 31) / 32, 3);
    conv_kernel<<<grid, dim3(256), 0, stream>>>(in, kout, out);
}